// Round 12
// baseline (452.531 us; speedup 1.0000x reference)
//
#include <hip/hip_runtime.h>
#include <hip/hip_bf16.h>
#include <type_traits>

// Problem constants
#define Bb  2
#define Ss  2048
#define Hh  2048
#define NHh 16
#define HDd 128
#define Mm  (Bb * Ss)   // 4096 rows

typedef __attribute__((ext_vector_type(8))) short short8;  // 8 bf16 (4 VGPRs)
typedef __attribute__((ext_vector_type(4))) float f32x4;   // MFMA accumulator

#if __has_builtin(__builtin_amdgcn_exp2f)
#define EXPFN(x) __builtin_amdgcn_exp2f(x)
#define QSCALE 0.12751744416668577f   /* (1/sqrt(128)) * log2(e), folded into Q */
#else
#define EXPFN(x) __expf(x)
#define QSCALE 0.08838834764831845f   /* 1/sqrt(128) folded into Q */
#endif

__device__ __forceinline__ float bf2f(unsigned short u) {
    unsigned int x = ((unsigned int)u) << 16;
    return __builtin_bit_cast(float, x);
}
__device__ __forceinline__ unsigned short f2bf(float f) {
    unsigned int x = __builtin_bit_cast(unsigned int, f);
    x += 0x7fffu + ((x >> 16) & 1u);   // RNE
    return (unsigned short)(x >> 16);
}

// ---------------------------------------------------------------- fused cast fp32->bf16 (3 buffers, 1 launch)
// Segment sizes in blocks: X=8192, Wqkv=12288, Wout=4096 (each block: 256 thr x 1 float4).
__global__ __launch_bounds__(256) void cast3(const float* __restrict__ a, unsigned short* __restrict__ ao,
                                             const float* __restrict__ b, unsigned short* __restrict__ bo,
                                             const float* __restrict__ c, unsigned short* __restrict__ co) {
    const int bid = blockIdx.x;
    const float* in; unsigned short* out; int base;
    if (bid < 8192)        { in = a; out = ao; base = bid; }
    else if (bid < 20480)  { in = b; out = bo; base = bid - 8192; }
    else                   { in = c; out = co; base = bid - 20480; }
    const int i = (base * 256 + threadIdx.x) * 4;
    float4 f = *(const float4*)(in + i);
    ushort4 o;
    o.x = f2bf(f.x); o.y = f2bf(f.y); o.z = f2bf(f.z); o.w = f2bf(f.w);
    *(ushort4*)(out + i) = o;
}

// ---------------------------------------------------------------- GEMM: C = A * Bt^T + bias (128x128, m97)
// Proven kernel (R2/R11: qkv 162 us @634 TF; out-proj ~55 us). 88 VGPR + 64 AGPR -> 3 blocks/CU
// of implicit wave overlap (m114); qkv grid 1536 blocks = 2.0 exact rounds. 256^2 variants
// deleted (128-AGPR acc -> 1 block/CU -> slower). Bank conflicts (3.8e7) left as-is:
// T2 fix measured null on 2-barrier structures (regime gate, m230). Frozen.
template <typename OutT>
__global__ __launch_bounds__(256) void gemm_bt(const unsigned short* __restrict__ A,
                                               const unsigned short* __restrict__ Bt,
                                               const float* __restrict__ bias,
                                               OutT* __restrict__ C,
                                               int M, int N, int K) {
    __shared__ unsigned short As[128 * 64];
    __shared__ unsigned short Bs[128 * 64];
    const int tid  = threadIdx.x;
    const int lane = tid & 63;
    const int wave = tid >> 6;
    const int q4 = lane >> 4, l15 = lane & 15;
    const int m0 = blockIdx.y * 128, n0 = blockIdx.x * 128;
    const int wm = (wave >> 1) * 64, wn = (wave & 1) * 64;

    f32x4 acc[4][4] = {};

    for (int k0 = 0; k0 < K; k0 += 64) {
#pragma unroll
        for (int t = 0; t < 4; ++t) {
            const int chunk = t * 256 + tid;
            const int row = chunk >> 3, c8 = chunk & 7;
            const unsigned short* ga = A  + (size_t)(m0 + row) * K + (k0 + c8 * 8);
            const unsigned short* gb = Bt + (size_t)(n0 + row) * K + (k0 + c8 * 8);
            __builtin_amdgcn_global_load_lds((const __attribute__((address_space(1))) unsigned int*)ga,
                                             (__attribute__((address_space(3))) unsigned int*)(As + chunk * 8),
                                             16, 0, 0);
            __builtin_amdgcn_global_load_lds((const __attribute__((address_space(1))) unsigned int*)gb,
                                             (__attribute__((address_space(3))) unsigned int*)(Bs + chunk * 8),
                                             16, 0, 0);
        }
        __syncthreads();
#pragma unroll
        for (int kk = 0; kk < 2; ++kk) {
            short8 a[4], b[4];
#pragma unroll
            for (int i = 0; i < 4; ++i)
                a[i] = *(const short8*)(As + (wm + i * 16 + l15) * 64 + kk * 32 + q4 * 8);
#pragma unroll
            for (int j = 0; j < 4; ++j)
                b[j] = *(const short8*)(Bs + (wn + j * 16 + l15) * 64 + kk * 32 + q4 * 8);
#pragma unroll
            for (int i = 0; i < 4; ++i)
#pragma unroll
                for (int j = 0; j < 4; ++j)
                    acc[i][j] = __builtin_amdgcn_mfma_f32_16x16x32_bf16(a[i], b[j], acc[i][j], 0, 0, 0);
        }
        __syncthreads();
    }

#pragma unroll
    for (int i = 0; i < 4; ++i) {
#pragma unroll
        for (int j = 0; j < 4; ++j) {
            const int col = n0 + wn + j * 16 + l15;
            const float bv = bias[col];
            const size_t base = (size_t)(m0 + wm + i * 16 + q4 * 4) * N + col;
#pragma unroll
            for (int r = 0; r < 4; ++r) {
                float v = acc[i][j][r] + bv;
                if constexpr (std::is_same_v<OutT, float>)
                    C[base + (size_t)r * N] = v;
                else
                    C[base + (size_t)r * N] = f2bf(v);
            }
        }
    }
}

// ---------------------------------------------------------------- fused RoPE-repack + V-transpose (1 launch)
// blocks [0,4096): rope for (s = bx&2047, b = bx>>11); blocks [4096,6144): v_transpose.
// R12: rope branch VECTORIZED (G13 / Common-mistake #2): was 4 iters of scalar 2B
// loads/stores; now 1 pass, each thread owns 8 contiguous d of one (head, Q|K):
// short8 x1/x2 loads, float4 cos/sin, short8 stores. Wave-uniform Q/K split
// (waves 0-1 = Q, waves 2-3 = K); all vector indices compile-time.
__global__ __launch_bounds__(256) void rope_v(const unsigned short* __restrict__ qkv, // [B][S][3H] bf16
                                              const float* __restrict__ cosp,         // [S][HD]
                                              const float* __restrict__ sinp,
                                              unsigned short* __restrict__ Qr,
                                              unsigned short* __restrict__ Kr,
                                              unsigned short* __restrict__ Vt) {
    __shared__ unsigned short T[64 * 64];
    const int bx = blockIdx.x, tid = threadIdx.x;
    if (bx < 4096) {
        // ---- RoPE + repack Q,K to [B*NH][S][HD] (Q pre-scaled by QSCALE)
        const int s = bx & 2047, b = bx >> 11;
        const unsigned short* base = qkv + (size_t)(b * Ss + s) * (3 * Hh);
        const int u = tid & 127;              // 0..127: 16 heads x 8 groups of 8 d's
        const int isK = tid >> 7;             // waves 0-1 -> Q, waves 2-3 -> K (uniform)
        const int h = u >> 3, d0 = (u & 7) * 8;   // d0 in [0,64), 8 contiguous d's
        const unsigned short* src = base + isK * Hh + h * HDd;
        short8 x1 = *(const short8*)(src + d0);        // x[d0..d0+7]
        short8 x2 = *(const short8*)(src + d0 + 64);   // x[d0+64..d0+71]
        float4 c0 = *(const float4*)(cosp + s * HDd + d0);
        float4 c1 = *(const float4*)(cosp + s * HDd + d0 + 4);
        float4 sn0 = *(const float4*)(sinp + s * HDd + d0);
        float4 sn1 = *(const float4*)(sinp + s * HDd + d0 + 4);
        const float cs[8]  = {c0.x, c0.y, c0.z, c0.w, c1.x, c1.y, c1.z, c1.w};
        const float sns[8] = {sn0.x, sn0.y, sn0.z, sn0.w, sn1.x, sn1.y, sn1.z, sn1.w};
        const float scale = isK ? 1.f : QSCALE;
        short8 o1, o2;
#pragma unroll
        for (int j = 0; j < 8; ++j) {
            const float a = bf2f((unsigned short)x1[j]);
            const float bb = bf2f((unsigned short)x2[j]);
            o1[j] = (short)f2bf((a * cs[j] - bb * sns[j]) * scale);
            o2[j] = (short)f2bf((bb * cs[j] + a * sns[j]) * scale);
        }
        unsigned short* dst = (isK ? Kr : Qr) + ((size_t)(b * NHh + h) * Ss + s) * HDd;
        *(short8*)(dst + d0)      = o1;
        *(short8*)(dst + d0 + 64) = o2;
    } else {
        // ---- V transpose: qkv V-part -> Vt [B*NH][HD][S], 64x64 XOR-swizzled tile
        const int t = bx - 4096;              // 0..2047
        const int st = t & 31;                // s-tile
        const int dt = (t >> 5) & 1;          // d-tile
        const int bh = t >> 6;                // 0..31
        const int b = bh >> 4, h = bh & 15;
#pragma unroll
        for (int it = 0; it < 2; ++it) {
            const int chunk = it * 256 + tid;
            const int row = chunk >> 3, c8 = chunk & 7;
            const unsigned short* src = qkv + ((size_t)(b * Ss + st * 64 + row)) * (3 * Hh)
                                            + 2 * Hh + h * HDd + dt * 64 + c8 * 8;
            uint4 v = *(const uint4*)src;
            *(uint4*)(T + row * 64 + ((c8 ^ (row & 7)) * 8)) = v;
        }
        __syncthreads();
#pragma unroll
        for (int it = 0; it < 2; ++it) {
            const int chunk = it * 256 + tid;
            const int drow = chunk & 63;
            const int c8s = chunk >> 6;
            ushort4 lo, hi;
            unsigned short tmp[8];
#pragma unroll
            for (int j = 0; j < 8; ++j) {
                const int sl = c8s * 8 + j;
                tmp[j] = T[sl * 64 + (((drow >> 3) ^ (sl & 7)) * 8) + (drow & 7)];
            }
            lo.x = tmp[0]; lo.y = tmp[1]; lo.z = tmp[2]; lo.w = tmp[3];
            hi.x = tmp[4]; hi.y = tmp[5]; hi.z = tmp[6]; hi.w = tmp[7];
            unsigned short* dst = Vt + ((size_t)bh * HDd + dt * 64 + drow) * Ss + st * 64 + c8s * 8;
            *(ushort4*)(dst)     = lo;
            *(ushort4*)(dst + 4) = hi;
        }
    }
}

// ---------------------------------------------------------------- flash attention (causal, FA2-paired)
// R6-VERIFIED version. 8 waves/block (512 thr): waves 0-3 own qA=blockIdx.x strips,
// waves 4-7 own qB=31-qA. KV tile staged once per block, shared by both q-tiles.
// LDS 50.4 KB -> 2 blocks/CU (grid 512 = exactly 2/CU resident; cross-block overlap hides
// the staging drain). R8 (V-reg, 3rd barrier) and R10 (full dbuf, 84 KB -> 1 block/CU)
// both measured WORSE (-8 us, -80 us). This structure is the measured optimum; frozen.
__global__ __launch_bounds__(512, 4) void attn_fwd(const unsigned short* __restrict__ Qr,
                                                   const unsigned short* __restrict__ Kr,
                                                   const unsigned short* __restrict__ Vt,
                                                   unsigned short* __restrict__ AO) {  // [B][S][H] bf16
    __shared__ unsigned short Ks[16 * 64 * 8];
    __shared__ unsigned short VtS[16 * 64 * 8];
    __shared__ unsigned short Ps[8][16 * 72];
    const int tid = threadIdx.x;
    const int lane = tid & 63, wave = tid >> 6;
    const int q4 = lane >> 4, l15 = lane & 15;
    const int qA = (int)blockIdx.x;
    const int qB = 31 - qA;
    const int bh = blockIdx.y;
    const int b = bh >> 4, h = bh & 15;
    const unsigned short* Qh  = Qr + (size_t)bh * Ss * HDd;
    const unsigned short* Kh  = Kr + (size_t)bh * Ss * HDd;
    const unsigned short* Vth = Vt + (size_t)bh * HDd * Ss;

    const int mt = wave >> 2;
    const int wg = wave & 3;
    const int s0 = (mt ? qB : qA) * 64 + wg * 16;

    short8 qf[4];
#pragma unroll
    for (int kc = 0; kc < 4; ++kc)
        qf[kc] = *(const short8*)(Qh + (size_t)(s0 + l15) * HDd + kc * 32 + q4 * 8);

    f32x4 o_acc[8] = {};
    float m_i[4], l_i[4];
#pragma unroll
    for (int r = 0; r < 4; ++r) { m_i[r] = -1e30f; l_i[r] = 0.f; }

    const int kv_end = qB * 64 + 64;
    for (int t0 = 0; t0 < kv_end; t0 += 64) {
#pragma unroll
        for (int it = 0; it < 2; ++it) {
            const int s = it * 8 + wave;
            const int g = s >> 2, kc = s & 3;
            const unsigned short* gk = Kh + (size_t)(t0 + g * 16 + l15) * HDd + kc * 32 + q4 * 8;
            __builtin_amdgcn_global_load_lds((const __attribute__((address_space(1))) unsigned int*)gk,
                                             (__attribute__((address_space(3))) unsigned int*)(Ks + (s * 64 + lane) * 8),
                                             16, 0, 0);
        }
#pragma unroll
        for (int it = 0; it < 2; ++it) {
            const int s = it * 8 + wave;
            const int n = s >> 1, ks = s & 1;
            const unsigned short* gv = Vth + (size_t)(n * 16 + l15) * Ss + t0 + ks * 32 + q4 * 8;
            __builtin_amdgcn_global_load_lds((const __attribute__((address_space(1))) unsigned int*)gv,
                                             (__attribute__((address_space(3))) unsigned int*)(VtS + (s * 64 + lane) * 8),
                                             16, 0, 0);
        }
        __syncthreads();

        if (t0 <= s0 + 15) {
            float sv[4][4];
#pragma unroll
            for (int g = 0; g < 4; ++g)
#pragma unroll
                for (int r = 0; r < 4; ++r) sv[g][r] = -1e30f;
#pragma unroll
            for (int g = 0; g < 4; ++g) {
                if (t0 + g * 16 <= s0 + 15) {
                    f32x4 scg = {};
#pragma unroll
                    for (int kc = 0; kc < 4; ++kc) {
                        short8 kf = *(const short8*)(Ks + ((g * 4 + kc) * 64 + lane) * 8);
                        scg = __builtin_amdgcn_mfma_f32_16x16x32_bf16(qf[kc], kf, scg, 0, 0, 0);
                    }
                    const int key = t0 + g * 16 + l15;
#pragma unroll
                    for (int r = 0; r < 4; ++r)
                        sv[g][r] = (key <= s0 + q4 * 4 + r) ? scg[r] : -1e30f;
                }
            }
            float mnew[4], alpha[4], sm[4];
            bool need = false;
#pragma unroll
            for (int r = 0; r < 4; ++r) {
                float mx = fmaxf(fmaxf(sv[0][r], sv[1][r]), fmaxf(sv[2][r], sv[3][r]));
#pragma unroll
                for (int off = 1; off < 16; off <<= 1)
                    mx = fmaxf(mx, __shfl_xor(mx, off, 16));
                mnew[r]  = fmaxf(m_i[r], mx);
                need = need || (mnew[r] > m_i[r]);
                alpha[r] = EXPFN(m_i[r] - mnew[r]);
                m_i[r] = mnew[r];
            }
            float p[4][4];
#pragma unroll
            for (int g = 0; g < 4; ++g)
#pragma unroll
                for (int r = 0; r < 4; ++r)
                    p[g][r] = EXPFN(sv[g][r] - mnew[r]);
#pragma unroll
            for (int r = 0; r < 4; ++r) {
                float s2 = (p[0][r] + p[1][r]) + (p[2][r] + p[3][r]);
#pragma unroll
                for (int off = 1; off < 16; off <<= 1)
                    s2 += __shfl_xor(s2, off, 16);
                sm[r] = s2;
            }
            if (__any(need)) {
#pragma unroll
                for (int r = 0; r < 4; ++r) l_i[r] *= alpha[r];
#pragma unroll
                for (int n = 0; n < 8; ++n)
#pragma unroll
                    for (int r = 0; r < 4; ++r)
                        o_acc[n][r] *= alpha[r];
            }
#pragma unroll
            for (int r = 0; r < 4; ++r) l_i[r] += sm[r];

            unsigned short* Pw = &Ps[wave][0];
#pragma unroll
            for (int g = 0; g < 4; ++g)
#pragma unroll
                for (int r = 0; r < 4; ++r)
                    Pw[(q4 * 4 + r) * 72 + g * 16 + l15] = f2bf(p[g][r]);

#pragma unroll
            for (int ks = 0; ks < 2; ++ks) {
                if (t0 + ks * 32 <= s0 + 15) {
                    short8 pfk = *(const short8*)(Pw + l15 * 72 + ks * 32 + q4 * 8);
#pragma unroll
                    for (int n = 0; n < 8; ++n) {
                        short8 vf = *(const short8*)(VtS + ((n * 2 + ks) * 64 + lane) * 8);
                        o_acc[n] = __builtin_amdgcn_mfma_f32_16x16x32_bf16(pfk, vf, o_acc[n], 0, 0, 0);
                    }
                }
            }
        }
        __syncthreads();
    }

    float inv[4];
#pragma unroll
    for (int r = 0; r < 4; ++r) inv[r] = 1.f / l_i[r];
#pragma unroll
    for (int n = 0; n < 8; ++n)
#pragma unroll
        for (int r = 0; r < 4; ++r) {
            const int query = s0 + q4 * 4 + r;
            AO[((size_t)(b * Ss + query)) * Hh + h * HDd + n * 16 + l15] = f2bf(o_acc[n][r] * inv[r]);
        }
}

// ---------------------------------------------------------------- host
extern "C" void kernel_launch(void* const* d_in, const int* in_sizes, int n_in,
                              void* d_out, int out_size, void* d_ws, size_t ws_size,
                              hipStream_t stream) {
    const float* X    = (const float*)d_in[0];
    const float* cosp = (const float*)d_in[1];
    const float* sinp = (const float*)d_in[2];
    const float* Wqkv = (const float*)d_in[3];
    const float* bqkv = (const float*)d_in[4];
    const float* Wout = (const float*)d_in[5];
    const float* bout = (const float*)d_in[6];
    float* out = (float*)d_out;

    char* ws = (char*)d_ws;
    size_t off = 0;
    auto carve = [&](size_t bytes) { void* p = ws + off; off += bytes; return p; };
    unsigned short* Xb    = (unsigned short*)carve((size_t)Mm * Hh * 2);        // 16 MB
    unsigned short* Wqkvb = (unsigned short*)carve((size_t)3 * Hh * Hh * 2);    // 24 MB
    unsigned short* Woutb = (unsigned short*)carve((size_t)Hh * Hh * 2);        //  8 MB
    unsigned short* QKVb  = (unsigned short*)carve((size_t)Mm * 3 * Hh * 2);    // 48 MB
    unsigned short* Qr    = (unsigned short*)carve((size_t)Mm * Hh * 2);        // 16 MB
    unsigned short* Kr    = (unsigned short*)carve((size_t)Mm * Hh * 2);        // 16 MB
    unsigned short* Vt    = (unsigned short*)carve((size_t)Mm * Hh * 2);        // 16 MB
    unsigned short* AOb   = (unsigned short*)carve((size_t)Mm * Hh * 2);        // 16 MB

    // 5 launches: cast3 -> gemm_bt(qkv) -> rope_v -> attn -> gemm_bt(out)
    cast3<<<24576, 256, 0, stream>>>(X, Xb, Wqkv, Wqkvb, Wout, Woutb);

    gemm_bt<unsigned short><<<dim3((3 * Hh) / 128, Mm / 128), 256, 0, stream>>>(
        Xb, Wqkvb, bqkv, QKVb, Mm, 3 * Hh, Hh);

    rope_v<<<6144, 256, 0, stream>>>(QKVb, cosp, sinp, Qr, Kr, Vt);

    attn_fwd<<<dim3(Ss / 128, Bb * NHh), 512, 0, stream>>>(Qr, Kr, Vt, AOb);

    gemm_bt<float><<<dim3(Hh / 128, Mm / 128), 256, 0, stream>>>(
        AOb, Woutb, bout, out, Mm, Hh, Hh);
}

// Round 15
// 448.881 us; speedup vs baseline: 1.0081x; 1.0081x over previous
//
#include <hip/hip_runtime.h>
#include <hip/hip_bf16.h>
#include <type_traits>

// Problem constants
#define Bb  2
#define Ss  2048
#define Hh  2048
#define NHh 16
#define HDd 128
#define Mm  (Bb * Ss)   // 4096 rows

typedef __attribute__((ext_vector_type(8))) short short8;  // 8 bf16 (4 VGPRs)
typedef __attribute__((ext_vector_type(4))) float f32x4;   // MFMA accumulator

#if __has_builtin(__builtin_amdgcn_exp2f)
#define EXPFN(x) __builtin_amdgcn_exp2f(x)
#define QSCALE 0.12751744416668577f   /* (1/sqrt(128)) * log2(e), folded into Q */
#else
#define EXPFN(x) __expf(x)
#define QSCALE 0.08838834764831845f   /* 1/sqrt(128) folded into Q */
#endif

__device__ __forceinline__ float bf2f(unsigned short u) {
    unsigned int x = ((unsigned int)u) << 16;
    return __builtin_bit_cast(float, x);
}
__device__ __forceinline__ unsigned short f2bf(float f) {
    unsigned int x = __builtin_bit_cast(unsigned int, f);
    x += 0x7fffu + ((x >> 16) & 1u);   // RNE
    return (unsigned short)(x >> 16);
}

// ---------------------------------------------------------------- fused cast fp32->bf16 (3 buffers, 1 launch)
// Segment sizes in blocks: X=8192, Wqkv=12288, Wout=4096 (each block: 256 thr x 1 float4).
__global__ __launch_bounds__(256) void cast3(const float* __restrict__ a, unsigned short* __restrict__ ao,
                                             const float* __restrict__ b, unsigned short* __restrict__ bo,
                                             const float* __restrict__ c, unsigned short* __restrict__ co) {
    const int bid = blockIdx.x;
    const float* in; unsigned short* out; int base;
    if (bid < 8192)        { in = a; out = ao; base = bid; }
    else if (bid < 20480)  { in = b; out = bo; base = bid - 8192; }
    else                   { in = c; out = co; base = bid - 20480; }
    const int i = (base * 256 + threadIdx.x) * 4;
    float4 f = *(const float4*)(in + i);
    ushort4 o;
    o.x = f2bf(f.x); o.y = f2bf(f.y); o.z = f2bf(f.z); o.w = f2bf(f.w);
    *(ushort4*)(out + i) = o;
}

// ---------------------------------------------------------------- GEMM: C = A * Bt^T + bias (128x128, m97)
// Proven kernel (R2/R11: qkv ~163 us @630 TF; out-proj ~55 us). 88 VGPR + 64 AGPR -> 3 blocks/CU
// of implicit wave overlap (m114); qkv grid 1536 blocks = 2.0 exact rounds. 256^2 variants
// deleted (128-AGPR acc -> 1 block/CU -> slower). Bank conflicts (3.8e7) left as-is (T2 null
// on 2-barrier structures, m230). NO setprio here (m190: measured negative on GEMM). Frozen.
template <typename OutT>
__global__ __launch_bounds__(256) void gemm_bt(const unsigned short* __restrict__ A,
                                               const unsigned short* __restrict__ Bt,
                                               const float* __restrict__ bias,
                                               OutT* __restrict__ C,
                                               int M, int N, int K) {
    __shared__ unsigned short As[128 * 64];
    __shared__ unsigned short Bs[128 * 64];
    const int tid  = threadIdx.x;
    const int lane = tid & 63;
    const int wave = tid >> 6;
    const int q4 = lane >> 4, l15 = lane & 15;
    const int m0 = blockIdx.y * 128, n0 = blockIdx.x * 128;
    const int wm = (wave >> 1) * 64, wn = (wave & 1) * 64;

    f32x4 acc[4][4] = {};

    for (int k0 = 0; k0 < K; k0 += 64) {
#pragma unroll
        for (int t = 0; t < 4; ++t) {
            const int chunk = t * 256 + tid;
            const int row = chunk >> 3, c8 = chunk & 7;
            const unsigned short* ga = A  + (size_t)(m0 + row) * K + (k0 + c8 * 8);
            const unsigned short* gb = Bt + (size_t)(n0 + row) * K + (k0 + c8 * 8);
            __builtin_amdgcn_global_load_lds((const __attribute__((address_space(1))) unsigned int*)ga,
                                             (__attribute__((address_space(3))) unsigned int*)(As + chunk * 8),
                                             16, 0, 0);
            __builtin_amdgcn_global_load_lds((const __attribute__((address_space(1))) unsigned int*)gb,
                                             (__attribute__((address_space(3))) unsigned int*)(Bs + chunk * 8),
                                             16, 0, 0);
        }
        __syncthreads();
#pragma unroll
        for (int kk = 0; kk < 2; ++kk) {
            short8 a[4], b[4];
#pragma unroll
            for (int i = 0; i < 4; ++i)
                a[i] = *(const short8*)(As + (wm + i * 16 + l15) * 64 + kk * 32 + q4 * 8);
#pragma unroll
            for (int j = 0; j < 4; ++j)
                b[j] = *(const short8*)(Bs + (wn + j * 16 + l15) * 64 + kk * 32 + q4 * 8);
#pragma unroll
            for (int i = 0; i < 4; ++i)
#pragma unroll
                for (int j = 0; j < 4; ++j)
                    acc[i][j] = __builtin_amdgcn_mfma_f32_16x16x32_bf16(a[i], b[j], acc[i][j], 0, 0, 0);
        }
        __syncthreads();
    }

#pragma unroll
    for (int i = 0; i < 4; ++i) {
#pragma unroll
        for (int j = 0; j < 4; ++j) {
            const int col = n0 + wn + j * 16 + l15;
            const float bv = bias[col];
            const size_t base = (size_t)(m0 + wm + i * 16 + q4 * 4) * N + col;
#pragma unroll
            for (int r = 0; r < 4; ++r) {
                float v = acc[i][j][r] + bv;
                if constexpr (std::is_same_v<OutT, float>)
                    C[base + (size_t)r * N] = v;
                else
                    C[base + (size_t)r * N] = f2bf(v);
            }
        }
    }
}

// ---------------------------------------------------------------- fused RoPE-repack + V-transpose (1 launch)
// blocks [0,4096): rope for (s = bx&2047, b = bx>>11); blocks [4096,6144): v_transpose.
// rope branch vectorized (R12: neutral vs scalar — already segment-coalesced & BW-bound; kept).
__global__ __launch_bounds__(256) void rope_v(const unsigned short* __restrict__ qkv, // [B][S][3H] bf16
                                              const float* __restrict__ cosp,         // [S][HD]
                                              const float* __restrict__ sinp,
                                              unsigned short* __restrict__ Qr,
                                              unsigned short* __restrict__ Kr,
                                              unsigned short* __restrict__ Vt) {
    __shared__ unsigned short T[64 * 64];
    const int bx = blockIdx.x, tid = threadIdx.x;
    if (bx < 4096) {
        // ---- RoPE + repack Q,K to [B*NH][S][HD] (Q pre-scaled by QSCALE)
        const int s = bx & 2047, b = bx >> 11;
        const unsigned short* base = qkv + (size_t)(b * Ss + s) * (3 * Hh);
        const int u = tid & 127;              // 0..127: 16 heads x 8 groups of 8 d's
        const int isK = tid >> 7;             // waves 0-1 -> Q, waves 2-3 -> K (uniform)
        const int h = u >> 3, d0 = (u & 7) * 8;   // d0 in [0,64), 8 contiguous d's
        const unsigned short* src = base + isK * Hh + h * HDd;
        short8 x1 = *(const short8*)(src + d0);        // x[d0..d0+7]
        short8 x2 = *(const short8*)(src + d0 + 64);   // x[d0+64..d0+71]
        float4 c0 = *(const float4*)(cosp + s * HDd + d0);
        float4 c1 = *(const float4*)(cosp + s * HDd + d0 + 4);
        float4 sn0 = *(const float4*)(sinp + s * HDd + d0);
        float4 sn1 = *(const float4*)(sinp + s * HDd + d0 + 4);
        const float cs[8]  = {c0.x, c0.y, c0.z, c0.w, c1.x, c1.y, c1.z, c1.w};
        const float sns[8] = {sn0.x, sn0.y, sn0.z, sn0.w, sn1.x, sn1.y, sn1.z, sn1.w};
        const float scale = isK ? 1.f : QSCALE;
        short8 o1, o2;
#pragma unroll
        for (int j = 0; j < 8; ++j) {
            const float a = bf2f((unsigned short)x1[j]);
            const float bb = bf2f((unsigned short)x2[j]);
            o1[j] = (short)f2bf((a * cs[j] - bb * sns[j]) * scale);
            o2[j] = (short)f2bf((bb * cs[j] + a * sns[j]) * scale);
        }
        unsigned short* dst = (isK ? Kr : Qr) + ((size_t)(b * NHh + h) * Ss + s) * HDd;
        *(short8*)(dst + d0)      = o1;
        *(short8*)(dst + d0 + 64) = o2;
    } else {
        // ---- V transpose: qkv V-part -> Vt [B*NH][HD][S], 64x64 XOR-swizzled tile
        const int t = bx - 4096;              // 0..2047
        const int st = t & 31;                // s-tile
        const int dt = (t >> 5) & 1;          // d-tile
        const int bh = t >> 6;                // 0..31
        const int b = bh >> 4, h = bh & 15;
#pragma unroll
        for (int it = 0; it < 2; ++it) {
            const int chunk = it * 256 + tid;
            const int row = chunk >> 3, c8 = chunk & 7;
            const unsigned short* src = qkv + ((size_t)(b * Ss + st * 64 + row)) * (3 * Hh)
                                            + 2 * Hh + h * HDd + dt * 64 + c8 * 8;
            uint4 v = *(const uint4*)src;
            *(uint4*)(T + row * 64 + ((c8 ^ (row & 7)) * 8)) = v;
        }
        __syncthreads();
#pragma unroll
        for (int it = 0; it < 2; ++it) {
            const int chunk = it * 256 + tid;
            const int drow = chunk & 63;
            const int c8s = chunk >> 6;
            ushort4 lo, hi;
            unsigned short tmp[8];
#pragma unroll
            for (int j = 0; j < 8; ++j) {
                const int sl = c8s * 8 + j;
                tmp[j] = T[sl * 64 + (((drow >> 3) ^ (sl & 7)) * 8) + (drow & 7)];
            }
            lo.x = tmp[0]; lo.y = tmp[1]; lo.z = tmp[2]; lo.w = tmp[3];
            hi.x = tmp[4]; hi.y = tmp[5]; hi.z = tmp[6]; hi.w = tmp[7];
            unsigned short* dst = Vt + ((size_t)bh * HDd + dt * 64 + drow) * Ss + st * 64 + c8s * 8;
            *(ushort4*)(dst)     = lo;
            *(ushort4*)(dst + 4) = hi;
        }
    }
}

// ---------------------------------------------------------------- flash attention (causal, FA2-paired)
// R6-verified structure. 8 waves/block (512 thr): waves 0-3 own qA=blockIdx.x strips,
// waves 4-7 own qB=31-qA. KV tile staged once per block, shared by both q-tiles.
// LDS 50.4 KB -> 2 blocks/CU. R8/R10 staging restructures measured worse; staging frozen.
// R13/R14/R15: T5 setprio(1) around the QK^T and PV MFMA clusters (m191: +4-7% on attn,
// where co-resident waves sit at staggered phases — true here: A/B-wave split + 2 blocks/CU.
// NOT applied to gemm_bt: m190 measured it negative on barrier-lockstep GEMM).
// (R13/R14 benches were infra flakes — same double-failure pattern as R3/R4, which passed
// unchanged on third submit; setprio is a pure wave-local scheduler hint, no hang path.)
__global__ __launch_bounds__(512, 4) void attn_fwd(const unsigned short* __restrict__ Qr,
                                                   const unsigned short* __restrict__ Kr,
                                                   const unsigned short* __restrict__ Vt,
                                                   unsigned short* __restrict__ AO) {  // [B][S][H] bf16
    __shared__ unsigned short Ks[16 * 64 * 8];
    __shared__ unsigned short VtS[16 * 64 * 8];
    __shared__ unsigned short Ps[8][16 * 72];
    const int tid = threadIdx.x;
    const int lane = tid & 63, wave = tid >> 6;
    const int q4 = lane >> 4, l15 = lane & 15;
    const int qA = (int)blockIdx.x;
    const int qB = 31 - qA;
    const int bh = blockIdx.y;
    const int b = bh >> 4, h = bh & 15;
    const unsigned short* Qh  = Qr + (size_t)bh * Ss * HDd;
    const unsigned short* Kh  = Kr + (size_t)bh * Ss * HDd;
    const unsigned short* Vth = Vt + (size_t)bh * HDd * Ss;

    const int mt = wave >> 2;
    const int wg = wave & 3;
    const int s0 = (mt ? qB : qA) * 64 + wg * 16;

    short8 qf[4];
#pragma unroll
    for (int kc = 0; kc < 4; ++kc)
        qf[kc] = *(const short8*)(Qh + (size_t)(s0 + l15) * HDd + kc * 32 + q4 * 8);

    f32x4 o_acc[8] = {};
    float m_i[4], l_i[4];
#pragma unroll
    for (int r = 0; r < 4; ++r) { m_i[r] = -1e30f; l_i[r] = 0.f; }

    const int kv_end = qB * 64 + 64;
    for (int t0 = 0; t0 < kv_end; t0 += 64) {
#pragma unroll
        for (int it = 0; it < 2; ++it) {
            const int s = it * 8 + wave;
            const int g = s >> 2, kc = s & 3;
            const unsigned short* gk = Kh + (size_t)(t0 + g * 16 + l15) * HDd + kc * 32 + q4 * 8;
            __builtin_amdgcn_global_load_lds((const __attribute__((address_space(1))) unsigned int*)gk,
                                             (__attribute__((address_space(3))) unsigned int*)(Ks + (s * 64 + lane) * 8),
                                             16, 0, 0);
        }
#pragma unroll
        for (int it = 0; it < 2; ++it) {
            const int s = it * 8 + wave;
            const int n = s >> 1, ks = s & 1;
            const unsigned short* gv = Vth + (size_t)(n * 16 + l15) * Ss + t0 + ks * 32 + q4 * 8;
            __builtin_amdgcn_global_load_lds((const __attribute__((address_space(1))) unsigned int*)gv,
                                             (__attribute__((address_space(3))) unsigned int*)(VtS + (s * 64 + lane) * 8),
                                             16, 0, 0);
        }
        __syncthreads();

        if (t0 <= s0 + 15) {
            float sv[4][4];
#pragma unroll
            for (int g = 0; g < 4; ++g)
#pragma unroll
                for (int r = 0; r < 4; ++r) sv[g][r] = -1e30f;
            __builtin_amdgcn_s_setprio(1);
#pragma unroll
            for (int g = 0; g < 4; ++g) {
                if (t0 + g * 16 <= s0 + 15) {
                    f32x4 scg = {};
#pragma unroll
                    for (int kc = 0; kc < 4; ++kc) {
                        short8 kf = *(const short8*)(Ks + ((g * 4 + kc) * 64 + lane) * 8);
                        scg = __builtin_amdgcn_mfma_f32_16x16x32_bf16(qf[kc], kf, scg, 0, 0, 0);
                    }
                    const int key = t0 + g * 16 + l15;
#pragma unroll
                    for (int r = 0; r < 4; ++r)
                        sv[g][r] = (key <= s0 + q4 * 4 + r) ? scg[r] : -1e30f;
                }
            }
            __builtin_amdgcn_s_setprio(0);
            float mnew[4], alpha[4], sm[4];
            bool need = false;
#pragma unroll
            for (int r = 0; r < 4; ++r) {
                float mx = fmaxf(fmaxf(sv[0][r], sv[1][r]), fmaxf(sv[2][r], sv[3][r]));
#pragma unroll
                for (int off = 1; off < 16; off <<= 1)
                    mx = fmaxf(mx, __shfl_xor(mx, off, 16));
                mnew[r]  = fmaxf(m_i[r], mx);
                need = need || (mnew[r] > m_i[r]);
                alpha[r] = EXPFN(m_i[r] - mnew[r]);
                m_i[r] = mnew[r];
            }
            float p[4][4];
#pragma unroll
            for (int g = 0; g < 4; ++g)
#pragma unroll
                for (int r = 0; r < 4; ++r)
                    p[g][r] = EXPFN(sv[g][r] - mnew[r]);
#pragma unroll
            for (int r = 0; r < 4; ++r) {
                float s2 = (p[0][r] + p[1][r]) + (p[2][r] + p[3][r]);
#pragma unroll
                for (int off = 1; off < 16; off <<= 1)
                    s2 += __shfl_xor(s2, off, 16);
                sm[r] = s2;
            }
            if (__any(need)) {
#pragma unroll
                for (int r = 0; r < 4; ++r) l_i[r] *= alpha[r];
#pragma unroll
                for (int n = 0; n < 8; ++n)
#pragma unroll
                    for (int r = 0; r < 4; ++r)
                        o_acc[n][r] *= alpha[r];
            }
#pragma unroll
            for (int r = 0; r < 4; ++r) l_i[r] += sm[r];

            unsigned short* Pw = &Ps[wave][0];
#pragma unroll
            for (int g = 0; g < 4; ++g)
#pragma unroll
                for (int r = 0; r < 4; ++r)
                    Pw[(q4 * 4 + r) * 72 + g * 16 + l15] = f2bf(p[g][r]);

            __builtin_amdgcn_s_setprio(1);
#pragma unroll
            for (int ks = 0; ks < 2; ++ks) {
                if (t0 + ks * 32 <= s0 + 15) {
                    short8 pfk = *(const short8*)(Pw + l15 * 72 + ks * 32 + q4 * 8);
#pragma unroll
                    for (int n = 0; n < 8; ++n) {
                        short8 vf = *(const short8*)(VtS + ((n * 2 + ks) * 64 + lane) * 8);
                        o_acc[n] = __builtin_amdgcn_mfma_f32_16x16x32_bf16(pfk, vf, o_acc[n], 0, 0, 0);
                    }
                }
            }
            __builtin_amdgcn_s_setprio(0);
        }
        __syncthreads();
    }

    float inv[4];
#pragma unroll
    for (int r = 0; r < 4; ++r) inv[r] = 1.f / l_i[r];
#pragma unroll
    for (int n = 0; n < 8; ++n)
#pragma unroll
        for (int r = 0; r < 4; ++r) {
            const int query = s0 + q4 * 4 + r;
            AO[((size_t)(b * Ss + query)) * Hh + h * HDd + n * 16 + l15] = f2bf(o_acc[n][r] * inv[r]);
        }
}

// ---------------------------------------------------------------- host
extern "C" void kernel_launch(void* const* d_in, const int* in_sizes, int n_in,
                              void* d_out, int out_size, void* d_ws, size_t ws_size,
                              hipStream_t stream) {
    const float* X    = (const float*)d_in[0];
    const float* cosp = (const float*)d_in[1];
    const float* sinp = (const float*)d_in[2];
    const float* Wqkv = (const float*)d_in[3];
    const float* bqkv = (const float*)d_in[4];
    const float* Wout = (const float*)d_in[5];
    const float* bout = (const float*)d_in[6];
    float* out = (float*)d_out;

    char* ws = (char*)d_ws;
    size_t off = 0;
    auto carve = [&](size_t bytes) { void* p = ws + off; off += bytes; return p; };
    unsigned short* Xb    = (unsigned short*)carve((size_t)Mm * Hh * 2);        // 16 MB
    unsigned short* Wqkvb = (unsigned short*)carve((size_t)3 * Hh * Hh * 2);    // 24 MB
    unsigned short* Woutb = (unsigned short*)carve((size_t)Hh * Hh * 2);        //  8 MB
    unsigned short* QKVb  = (unsigned short*)carve((size_t)Mm * 3 * Hh * 2);    // 48 MB
    unsigned short* Qr    = (unsigned short*)carve((size_t)Mm * Hh * 2);        // 16 MB
    unsigned short* Kr    = (unsigned short*)carve((size_t)Mm * Hh * 2);        // 16 MB
    unsigned short* Vt    = (unsigned short*)carve((size_t)Mm * Hh * 2);        // 16 MB
    unsigned short* AOb   = (unsigned short*)carve((size_t)Mm * Hh * 2);        // 16 MB

    // 5 launches: cast3 -> gemm_bt(qkv) -> rope_v -> attn -> gemm_bt(out)
    cast3<<<24576, 256, 0, stream>>>(X, Xb, Wqkv, Wqkvb, Wout, Woutb);

    gemm_bt<unsigned short><<<dim3((3 * Hh) / 128, Mm / 128), 256, 0, stream>>>(
        Xb, Wqkvb, bqkv, QKVb, Mm, 3 * Hh, Hh);

    rope_v<<<6144, 256, 0, stream>>>(QKVb, cosp, sinp, Qr, Kr, Vt);

    attn_fwd<<<dim3(Ss / 128, Bb * NHh), 512, 0, stream>>>(Qr, Kr, Vt, AOb);

    gemm_bt<float><<<dim3(Hh / 128, Mm / 128), 256, 0, stream>>>(
        AOb, Woutb, bout, out, Mm, Hh, Hh);
}